// Round 7
// baseline (455.381 us; speedup 1.0000x reference)
//
#include <hip/hip_runtime.h>
#include <hip/hip_fp16.h>

#define DH 256   // feature dim (D == H == 256)

typedef _Float16 half8 __attribute__((ext_vector_type(8)));
typedef float floatx4 __attribute__((ext_vector_type(4)));

// Layouts: X/A/h1 are stored SLICE-MAJOR f16: buf[slice][node][32], slice=f/32,
// i.e. region s is a contiguous n*64B block -> per-pass gather target is 3.2MB
// (L2-resident per XCD). Final out_h is row-major f32 (output format).

// ---------------------------------------------------------------- setup kernels

__global__ void k_init(float* __restrict__ deg, int* __restrict__ fill,
                       float* __restrict__ s, int n) {
    int i = blockIdx.x * blockDim.x + threadIdx.x;
    if (i < n) { deg[i] = 1.0f; fill[i] = 0; s[i] = 0.f; }
}

__global__ void k_deg(const int* __restrict__ dst, float* __restrict__ deg, int e) {
    int i = blockIdx.x * blockDim.x + threadIdx.x;
    if (i < e) atomicAdd(&deg[dst[i]], 1.0f);
}

// ---- hierarchical exclusive scan of (int)deg -> row_ptr[0..n]; also dinv ----
__global__ __launch_bounds__(1024) void k_scan1(const float* __restrict__ deg,
                                                float* __restrict__ dinv,
                                                int* __restrict__ row_ptr,
                                                int* __restrict__ part, int n) {
    __shared__ int sd[1024];
    int tid = threadIdx.x;
    int i = blockIdx.x * 1024 + tid;
    float dv = (i < n) ? deg[i] : 1.f;
    if (i < n) dinv[i] = rsqrtf(dv);
    int v = (i < n) ? (int)dv : 0;
    sd[tid] = v;
    __syncthreads();
    for (int off = 1; off < 1024; off <<= 1) {
        int t = (tid >= off) ? sd[tid - off] : 0;
        __syncthreads();
        sd[tid] += t;
        __syncthreads();
    }
    if (i < n) row_ptr[i] = sd[tid] - v;
    if (tid == 1023) part[blockIdx.x] = sd[1023];
}

__global__ void k_scan2(int* __restrict__ part, int* __restrict__ row_ptr,
                        int nparts, int n) {
    if (threadIdx.x == 0) {
        int run = 0;
        for (int b = 0; b < nparts; b++) {
            int t = part[b];
            part[b] = run;
            run += t;
        }
        row_ptr[n] = run;
    }
}

// phase 3: add block offsets; also write self-loop CSR entry
__global__ __launch_bounds__(1024) void k_scan3(int* __restrict__ row_ptr,
                                                const int* __restrict__ part,
                                                const float* __restrict__ dinv,
                                                int* __restrict__ col,
                                                float* __restrict__ wgt,
                                                int* __restrict__ fill, int n) {
    int i = blockIdx.x * 1024 + threadIdx.x;
    if (i < n) {
        int rp = row_ptr[i] + part[blockIdx.x];
        row_ptr[i] = rp;
        col[rp] = i;
        float d = dinv[i];
        wgt[rp] = d * d;
        fill[i] = 1;
    }
}

__global__ void k_csr(const int* __restrict__ src, const int* __restrict__ dst,
                      const float* __restrict__ dinv, const int* __restrict__ row_ptr,
                      int* __restrict__ fill, int* __restrict__ col,
                      float* __restrict__ wgt, int e) {
    int i = blockIdx.x * blockDim.x + threadIdx.x;
    if (i < e) {
        int s0 = src[i], d0 = dst[i];
        int p = row_ptr[d0] + atomicAdd(&fill[d0], 1);
        col[p] = s0;
        wgt[p] = dinv[s0] * dinv[d0];
    }
}

// transpose+cast: W[k][n] f32 -> Wt[n][k] f16  (256x256); z selects weight
__global__ __launch_bounds__(256) void k_tw(const float* __restrict__ W1,
                                            _Float16* __restrict__ Wt1,
                                            const float* __restrict__ W2,
                                            _Float16* __restrict__ Wt2) {
    const float* W = blockIdx.z ? W2 : W1;
    _Float16* Wt = blockIdx.z ? Wt2 : Wt1;
    __shared__ float t[32][33];
    int bx = blockIdx.x * 32, by = blockIdx.y * 32;
    int tx = threadIdx.x & 31, ty = threadIdx.x >> 5;
#pragma unroll
    for (int r = 0; r < 32; r += 8)
        t[ty + r][tx] = W[(size_t)(by + ty + r) * DH + bx + tx];
    __syncthreads();
#pragma unroll
    for (int r = 0; r < 32; r += 8)
        Wt[(size_t)(bx + ty + r) * DH + by + tx] = (_Float16)t[tx][ty + r];
}

// cast X f32 row-major -> f16 slice-major
__global__ __launch_bounds__(256) void k_xh(const float* __restrict__ x,
                                            _Float16* __restrict__ xh, int n) {
    int total = n * 32;   // groups of 8 f16
    int i = blockIdx.x * blockDim.x + threadIdx.x;
    int stride = gridDim.x * blockDim.x;
    for (int j = i; j < total; j += stride) {
        int node = j >> 5;
        int k8 = j & 31;            // 8-elem group within row, k = k8*8
        const float* p = x + (size_t)node * DH + k8 * 8;
        float4 a = *(const float4*)p;
        float4 b = *(const float4*)(p + 4);
        half8 h;
        h[0] = (_Float16)a.x; h[1] = (_Float16)a.y;
        h[2] = (_Float16)a.z; h[3] = (_Float16)a.w;
        h[4] = (_Float16)b.x; h[5] = (_Float16)b.y;
        h[6] = (_Float16)b.z; h[7] = (_Float16)b.w;
        int slice = k8 >> 2;
        int ko = (k8 & 3) * 8;
        *(half8*)(xh + (size_t)slice * n * 32 + (size_t)node * 32 + ko) = h;
    }
}

// ---------------------------------------------------------------- MFMA GEMM
// C[slice][m][32] = A[m][:] @ W.  W in registers; K-split two-phase register
// pipeline (VGPR ~120 -> 4 waves/SIMD). Input X slice-major f16.

__device__ __forceinline__ void gload_h(half8 (&buf)[4], int t, int h,
                                        int lm, int kg,
                                        const _Float16* __restrict__ Xh,
                                        size_t nsl, int n) {
    int m = min(t * 16 + lm, n - 1);
#pragma unroll
    for (int sp = 0; sp < 4; sp++)
        buf[sp] = *(const half8*)(Xh + (size_t)(h * 4 + sp) * nsl + (size_t)m * 32 + kg * 8);
}

__global__ __launch_bounds__(512, 3) void k_gemm_w(const _Float16* __restrict__ Xh,
                                                   const _Float16* __restrict__ Wt,
                                                   _Float16* __restrict__ C,
                                                   int n, int ntiles, int cpb) {
    int tid = threadIdx.x;
    int wave = tid >> 6, lane = tid & 63;
    int lm = lane & 15;
    int kg = lane >> 4;
    int c0 = wave * 32;
    size_t nsl = (size_t)n * 32;   // slice region elems

    half8 wfrag[2][8];
#pragma unroll
    for (int jj = 0; jj < 2; jj++)
#pragma unroll
        for (int s = 0; s < 8; s++)
            wfrag[jj][s] = *(const half8*)(Wt + (size_t)(c0 + jj * 16 + lm) * DH + s * 32 + kg * 8);

    int tstart = blockIdx.x * cpb;
    if (tstart >= ntiles) return;
    int tend = min(tstart + cpb, ntiles);

    half8 ba[4], bb[4];
    gload_h(ba, tstart, 0, lm, kg, Xh, nsl, n);

    for (int t = tstart; t < tend; t++) {
        gload_h(bb, t, 1, lm, kg, Xh, nsl, n);          // half 1 of current tile
        floatx4 acc0 = {0.f, 0.f, 0.f, 0.f};
        floatx4 acc1 = {0.f, 0.f, 0.f, 0.f};
#pragma unroll
        for (int sp = 0; sp < 4; sp++) {
            acc0 = __builtin_amdgcn_mfma_f32_16x16x32_f16(wfrag[0][sp], ba[sp], acc0, 0, 0, 0);
            acc1 = __builtin_amdgcn_mfma_f32_16x16x32_f16(wfrag[1][sp], ba[sp], acc1, 0, 0, 0);
        }
        gload_h(ba, t + 1, 0, lm, kg, Xh, nsl, n);      // half 0 of next tile
#pragma unroll
        for (int sp = 0; sp < 4; sp++) {
            acc0 = __builtin_amdgcn_mfma_f32_16x16x32_f16(wfrag[0][4 + sp], bb[sp], acc0, 0, 0, 0);
            acc1 = __builtin_amdgcn_mfma_f32_16x16x32_f16(wfrag[1][4 + sp], bb[sp], acc1, 0, 0, 0);
        }

        int m = t * 16 + lm;
        if (m < n) {
            // slice = wave; within-slice col = jj*16 + kg*4
            _Float16* cb = C + (size_t)wave * nsl + (size_t)m * 32 + kg * 4;
            __half2 h0 = __float22half2_rn(make_float2(acc0[0], acc0[1]));
            __half2 h1 = __float22half2_rn(make_float2(acc0[2], acc0[3]));
            uint2 u;
            u.x = *(unsigned int*)&h0; u.y = *(unsigned int*)&h1;
            *(uint2*)cb = u;
            h0 = __float22half2_rn(make_float2(acc1[0], acc1[1]));
            h1 = __float22half2_rn(make_float2(acc1[2], acc1[3]));
            u.x = *(unsigned int*)&h0; u.y = *(unsigned int*)&h1;
            *(uint2*)(cb + 16) = u;
        }
    }
}

// ---------------------------------------------------------------- aggregation
// grid (ceil(n/4), 8): y = feature slice (slow dim -> passes ~sequential, each
// pass gathers only a 3.2MB contiguous region). Wave = 1 node; 8 lane-groups
// handle 8 neighbors in parallel; cross-group shfl reduction.

#define AGG_SLICE_BODY                                                          \
    int node = blockIdx.x * 4 + (threadIdx.x >> 6);                             \
    if (node >= n) return;                                                      \
    int slice = blockIdx.y;                                                     \
    int lane = threadIdx.x & 63;                                                \
    int grp = lane >> 3, q = lane & 7;                                          \
    int p0 = row_ptr[node], p1 = row_ptr[node + 1];                             \
    const _Float16* As = A + (size_t)slice * n * 32 + q * 4;                    \
    float a0 = 0.f, a1 = 0.f, a2 = 0.f, a3 = 0.f;                               \
    for (int p = p0; p < p1; p += 16) {                                         \
        int idx0 = p + grp, idx1 = p + grp + 8;                                 \
        int c0 = col[min(idx0, p1 - 1)];                                        \
        int c1 = col[min(idx1, p1 - 1)];                                        \
        float w0 = (idx0 < p1) ? wgt[idx0] : 0.f;                               \
        float w1 = (idx1 < p1) ? wgt[idx1] : 0.f;                               \
        uint2 u0 = *(const uint2*)(As + (size_t)c0 * 32);                       \
        uint2 u1 = *(const uint2*)(As + (size_t)c1 * 32);                       \
        float2 f0a = __half22float2(*(__half2*)&u0.x);                          \
        float2 f0b = __half22float2(*(__half2*)&u0.y);                          \
        float2 f1a = __half22float2(*(__half2*)&u1.x);                          \
        float2 f1b = __half22float2(*(__half2*)&u1.y);                          \
        a0 += w0 * f0a.x + w1 * f1a.x;                                          \
        a1 += w0 * f0a.y + w1 * f1a.y;                                          \
        a2 += w0 * f0b.x + w1 * f1b.x;                                          \
        a3 += w0 * f0b.y + w1 * f1b.y;                                          \
    }                                                                           \
    a0 += __shfl_down(a0, 32); a1 += __shfl_down(a1, 32);                       \
    a2 += __shfl_down(a2, 32); a3 += __shfl_down(a3, 32);                       \
    a0 += __shfl_down(a0, 16); a1 += __shfl_down(a1, 16);                       \
    a2 += __shfl_down(a2, 16); a3 += __shfl_down(a3, 16);                       \
    a0 += __shfl_down(a0, 8);  a1 += __shfl_down(a1, 8);                        \
    a2 += __shfl_down(a2, 8);  a3 += __shfl_down(a3, 8);

// variant 1: f16 slice-major output (h1, feeds gemm2)
__global__ __launch_bounds__(256) void k_agg_h(const _Float16* __restrict__ A,
                                               const int* __restrict__ row_ptr,
                                               const int* __restrict__ col,
                                               const float* __restrict__ wgt,
                                               const float* __restrict__ bias,
                                               _Float16* __restrict__ out, int n) {
    AGG_SLICE_BODY
    if (grp == 0) {
        int f = slice * 32 + q * 4;
        float4 b4 = *(const float4*)&bias[f];
        __half2 h0 = __float22half2_rn(make_float2(fmaxf(a0 + b4.x, 0.f), fmaxf(a1 + b4.y, 0.f)));
        __half2 h1 = __float22half2_rn(make_float2(fmaxf(a2 + b4.z, 0.f), fmaxf(a3 + b4.w, 0.f)));
        uint2 u;
        u.x = *(unsigned int*)&h0;
        u.y = *(unsigned int*)&h1;
        *(uint2*)(out + (size_t)slice * n * 32 + (size_t)node * 32 + q * 4) = u;
    }
}

// variant 2: f32 row-major output (final h) + per-slice partial edge-pred dot
__global__ __launch_bounds__(256) void k_agg_f(const _Float16* __restrict__ A,
                                               const int* __restrict__ row_ptr,
                                               const int* __restrict__ col,
                                               const float* __restrict__ wgt,
                                               const float* __restrict__ bias,
                                               const float* __restrict__ We,
                                               float* __restrict__ out,
                                               float* __restrict__ s, int n) {
    AGG_SLICE_BODY
    float d = 0.f;
    if (grp == 0) {
        int f = slice * 32 + q * 4;
        float4 b4 = *(const float4*)&bias[f];
        float4 v = make_float4(fmaxf(a0 + b4.x, 0.f), fmaxf(a1 + b4.y, 0.f),
                               fmaxf(a2 + b4.z, 0.f), fmaxf(a3 + b4.w, 0.f));
        *(float4*)&out[(size_t)node * DH + f] = v;
        float4 wv = *(const float4*)&We[f];
        d = v.x * wv.x + v.y * wv.y + v.z * wv.z + v.w * wv.w;
    }
    d += __shfl_down(d, 4);
    d += __shfl_down(d, 2);
    d += __shfl_down(d, 1);
    if (lane == 0) atomicAdd(&s[node], d);
}

// ---------------------------------------------------------------- edge output

__global__ void k_y(const int* __restrict__ src, const int* __restrict__ dst,
                    const float* __restrict__ s, const float* __restrict__ be,
                    float* __restrict__ y, int e) {
    int i = blockIdx.x * blockDim.x + threadIdx.x;
    if (i < e) y[i] = 0.5f * (s[src[i]] + s[dst[i]]) + be[0];
}

// ---------------------------------------------------------------- launch

extern "C" void kernel_launch(void* const* d_in, const int* in_sizes, int n_in,
                              void* d_out, int out_size, void* d_ws, size_t ws_size,
                              hipStream_t stream) {
    const float* x  = (const float*)d_in[0];
    const int*   ei = (const int*)d_in[1];
    const float* W1 = (const float*)d_in[2];
    const float* b1 = (const float*)d_in[3];
    const float* W2 = (const float*)d_in[4];
    const float* b2 = (const float*)d_in[5];
    const float* We = (const float*)d_in[6];
    const float* be = (const float*)d_in[7];

    int n = in_sizes[0] / DH;
    int e = in_sizes[1] / 2;
    const int* src = ei;
    const int* dst = ei + e;

    float* out_h = (float*)d_out;                   // n*DH f32 (final, row-major)
    float* out_y = out_h + (size_t)n * DH;          // e
    // Xh (f16 slice-major cast of x) lives in the out_h region until agg_f writes.
    _Float16* Xh = (_Float16*)d_out;

    char* w = (char*)d_ws;
    _Float16* A   = (_Float16*)w;  w += ((size_t)n * DH * 2 + 255) & ~255ull;
    _Float16* h1  = (_Float16*)w;  w += ((size_t)n * DH * 2 + 255) & ~255ull;
    _Float16* Wt1 = (_Float16*)w;  w += (size_t)DH * DH * 2;
    _Float16* Wt2 = (_Float16*)w;  w += (size_t)DH * DH * 2;
    float* deg    = (float*)w;  w += (size_t)n * 4;
    float* dinv   = (float*)w;  w += (size_t)n * 4;
    int*   row_ptr= (int*)w;    w += (size_t)(n + 1) * 4;
    int*   fill   = (int*)w;    w += (size_t)n * 4;
    int*   col    = (int*)w;    w += (size_t)(e + n + 16) * 4;
    float* wgt    = (float*)w;  w += (size_t)(e + n + 16) * 4;
    float* sbuf   = (float*)w;  w += (size_t)n * 4;
    int*   part   = (int*)w;    w += 4096;

    const int tb = 256;
    int nscan = (n + 1023) / 1024;
    k_init<<<(n + tb - 1) / tb, tb, 0, stream>>>(deg, fill, sbuf, n);
    k_deg<<<(e + tb - 1) / tb, tb, 0, stream>>>(dst, deg, e);
    k_scan1<<<nscan, 1024, 0, stream>>>(deg, dinv, row_ptr, part, n);
    k_scan2<<<1, 64, 0, stream>>>(part, row_ptr, nscan, n);
    k_scan3<<<nscan, 1024, 0, stream>>>(row_ptr, part, dinv, col, wgt, fill, n);
    k_csr<<<(e + tb - 1) / tb, tb, 0, stream>>>(src, dst, dinv, row_ptr, fill, col, wgt, e);
    dim3 gt(8, 8, 2);
    k_tw<<<gt, 256, 0, stream>>>(W1, Wt1, W2, Wt2);
    k_xh<<<2048, 256, 0, stream>>>(x, Xh, n);

    int ntiles = (n + 15) / 16;
    int nblk = 512;
    int cpb = (ntiles + nblk - 1) / nblk;
    dim3 ga((n + 3) / 4, 8);
    k_gemm_w<<<nblk, 512, 0, stream>>>(Xh, Wt1, A, n, ntiles, cpb);             // A = x@W1
    k_agg_h<<<ga, 256, 0, stream>>>(A, row_ptr, col, wgt, b1, h1, n);           // h1 (sliced)
    k_gemm_w<<<nblk, 512, 0, stream>>>(h1, Wt2, A, n, ntiles, cpb);             // A = h1@W2
    k_agg_f<<<ga, 256, 0, stream>>>(A, row_ptr, col, wgt, b2, We, out_h, sbuf, n); // h + s
    k_y<<<(e + tb - 1) / tb, tb, 0, stream>>>(src, dst, sbuf, be, out_y, e);
}

// Round 8
// 320.053 us; speedup vs baseline: 1.4228x; 1.4228x over previous
//
#include <hip/hip_runtime.h>
#include <hip/hip_fp16.h>

#define DH 256   // feature dim (D == H == 256)

typedef _Float16 half8 __attribute__((ext_vector_type(8)));
typedef float floatx4 __attribute__((ext_vector_type(4)));

// ---------------------------------------------------------------- setup kernels

__global__ void k_init(float* __restrict__ deg, int* __restrict__ fill, int n) {
    int i = blockIdx.x * blockDim.x + threadIdx.x;
    if (i < n) { deg[i] = 1.0f; fill[i] = 0; }   // self-loop included in deg
}

__global__ void k_deg(const int* __restrict__ dst, float* __restrict__ deg, int e) {
    int i = blockIdx.x * blockDim.x + threadIdx.x;
    if (i < e) atomicAdd(&deg[dst[i]], 1.0f);
}

// ---- hierarchical exclusive scan of (int)deg -> row_ptr[0..n]; also dinv ----
__global__ __launch_bounds__(1024) void k_scan1(const float* __restrict__ deg,
                                                float* __restrict__ dinv,
                                                int* __restrict__ row_ptr,
                                                int* __restrict__ part, int n) {
    __shared__ int sd[1024];
    int tid = threadIdx.x;
    int i = blockIdx.x * 1024 + tid;
    float dv = (i < n) ? deg[i] : 1.f;
    if (i < n) dinv[i] = rsqrtf(dv);
    int v = (i < n) ? (int)dv : 0;
    sd[tid] = v;
    __syncthreads();
    for (int off = 1; off < 1024; off <<= 1) {
        int t = (tid >= off) ? sd[tid - off] : 0;
        __syncthreads();
        sd[tid] += t;
        __syncthreads();
    }
    if (i < n) row_ptr[i] = sd[tid] - v;
    if (tid == 1023) part[blockIdx.x] = sd[1023];
}

__global__ void k_scan2(int* __restrict__ part, int* __restrict__ row_ptr,
                        int nparts, int n) {
    if (threadIdx.x == 0) {
        int run = 0;
        for (int b = 0; b < nparts; b++) {
            int t = part[b];
            part[b] = run;
            run += t;
        }
        row_ptr[n] = run;
    }
}

// phase 3: add block offsets; also write self-loop CSR entry
__global__ __launch_bounds__(1024) void k_scan3(int* __restrict__ row_ptr,
                                                const int* __restrict__ part,
                                                const float* __restrict__ dinv,
                                                int* __restrict__ col,
                                                float* __restrict__ wgt,
                                                int* __restrict__ fill, int n) {
    int i = blockIdx.x * 1024 + threadIdx.x;
    if (i < n) {
        int rp = row_ptr[i] + part[blockIdx.x];
        row_ptr[i] = rp;
        col[rp] = i;
        float d = dinv[i];
        wgt[rp] = d * d;
        fill[i] = 1;
    }
}

__global__ void k_csr(const int* __restrict__ src, const int* __restrict__ dst,
                      const float* __restrict__ dinv, const int* __restrict__ row_ptr,
                      int* __restrict__ fill, int* __restrict__ col,
                      float* __restrict__ wgt, int e) {
    int i = blockIdx.x * blockDim.x + threadIdx.x;
    if (i < e) {
        int s0 = src[i], d0 = dst[i];
        int p = row_ptr[d0] + atomicAdd(&fill[d0], 1);
        col[p] = s0;
        wgt[p] = dinv[s0] * dinv[d0];
    }
}

// transpose+cast: W[k][n] f32 -> Wt[n][k] f16  (256x256); z selects weight
__global__ __launch_bounds__(256) void k_tw(const float* __restrict__ W1,
                                            _Float16* __restrict__ Wt1,
                                            const float* __restrict__ W2,
                                            _Float16* __restrict__ Wt2) {
    const float* W = blockIdx.z ? W2 : W1;
    _Float16* Wt = blockIdx.z ? Wt2 : Wt1;
    __shared__ float t[32][33];
    int bx = blockIdx.x * 32, by = blockIdx.y * 32;
    int tx = threadIdx.x & 31, ty = threadIdx.x >> 5;
#pragma unroll
    for (int r = 0; r < 32; r += 8)
        t[ty + r][tx] = W[(size_t)(by + ty + r) * DH + bx + tx];
    __syncthreads();
#pragma unroll
    for (int r = 0; r < 32; r += 8)
        Wt[(size_t)(bx + ty + r) * DH + by + tx] = (_Float16)t[tx][ty + r];
}

// cast X f32 -> f16 row-major (8 elems / thread / iter)
__global__ __launch_bounds__(256) void k_xh(const float* __restrict__ x,
                                            _Float16* __restrict__ xh, int elems8) {
    int i = blockIdx.x * blockDim.x + threadIdx.x;
    int stride = gridDim.x * blockDim.x;
    for (int j = i; j < elems8; j += stride) {
        const float* p = x + (size_t)j * 8;
        float4 a = *(const float4*)p;
        float4 b = *(const float4*)(p + 4);
        half8 h;
        h[0] = (_Float16)a.x; h[1] = (_Float16)a.y;
        h[2] = (_Float16)a.z; h[3] = (_Float16)a.w;
        h[4] = (_Float16)b.x; h[5] = (_Float16)b.y;
        h[6] = (_Float16)b.z; h[7] = (_Float16)b.w;
        *(half8*)(xh + (size_t)j * 8) = h;
    }
}

// ---------------------------------------------------------------- MFMA GEMM
// C[m][0:256] (f16) = A[m][0:256] @ W.  W in registers; K-split halves with a
// 4-buffer rotation (full next-tile prefetched while current computes).

__device__ __forceinline__ void gload_h(half8 (&buf)[4], int t, int h,
                                        int lm, int kg,
                                        const _Float16* __restrict__ Xh, int n) {
    int m = min(t * 16 + lm, n - 1);
    const _Float16* p = Xh + (size_t)m * DH + h * 128 + kg * 8;
#pragma unroll
    for (int sp = 0; sp < 4; sp++) buf[sp] = *(const half8*)(p + sp * 32);
}

__global__ __launch_bounds__(512, 3) void k_gemm_w(const _Float16* __restrict__ Xh,
                                                   const _Float16* __restrict__ Wt,
                                                   _Float16* __restrict__ C,
                                                   int n, int ntiles, int cpb) {
    int tid = threadIdx.x;
    int wave = tid >> 6, lane = tid & 63;
    int lm = lane & 15;
    int kg = lane >> 4;
    int c0 = wave * 32;

    half8 wfrag[2][8];
#pragma unroll
    for (int jj = 0; jj < 2; jj++)
#pragma unroll
        for (int s = 0; s < 8; s++)
            wfrag[jj][s] = *(const half8*)(Wt + (size_t)(c0 + jj * 16 + lm) * DH + s * 32 + kg * 8);

    int tstart = blockIdx.x * cpb;
    if (tstart >= ntiles) return;
    int tend = min(tstart + cpb, ntiles);

    half8 ba[4], bb[4], ca[4], cb[4];
    gload_h(ba, tstart, 0, lm, kg, Xh, n);
    gload_h(bb, tstart, 1, lm, kg, Xh, n);

    for (int t = tstart; t < tend; t++) {
        bool more = (t + 1) < tend;
        if (more) gload_h(ca, t + 1, 0, lm, kg, Xh, n);   // next tile, half 0

        floatx4 acc0 = {0.f, 0.f, 0.f, 0.f};
        floatx4 acc1 = {0.f, 0.f, 0.f, 0.f};
#pragma unroll
        for (int sp = 0; sp < 4; sp++) {
            acc0 = __builtin_amdgcn_mfma_f32_16x16x32_f16(wfrag[0][sp], ba[sp], acc0, 0, 0, 0);
            acc1 = __builtin_amdgcn_mfma_f32_16x16x32_f16(wfrag[1][sp], ba[sp], acc1, 0, 0, 0);
        }
        if (more) gload_h(cb, t + 1, 1, lm, kg, Xh, n);   // next tile, half 1
#pragma unroll
        for (int sp = 0; sp < 4; sp++) {
            acc0 = __builtin_amdgcn_mfma_f32_16x16x32_f16(wfrag[0][4 + sp], bb[sp], acc0, 0, 0, 0);
            acc1 = __builtin_amdgcn_mfma_f32_16x16x32_f16(wfrag[1][4 + sp], bb[sp], acc1, 0, 0, 0);
        }

        int m = t * 16 + lm;
        if (m < n) {
            _Float16* crow = C + (size_t)m * DH + c0 + kg * 4;
            __half2 h0 = __float22half2_rn(make_float2(acc0[0], acc0[1]));
            __half2 h1 = __float22half2_rn(make_float2(acc0[2], acc0[3]));
            uint2 u;
            u.x = *(unsigned int*)&h0; u.y = *(unsigned int*)&h1;
            *(uint2*)crow = u;
            h0 = __float22half2_rn(make_float2(acc1[0], acc1[1]));
            h1 = __float22half2_rn(make_float2(acc1[2], acc1[3]));
            u.x = *(unsigned int*)&h0; u.y = *(unsigned int*)&h1;
            *(uint2*)(crow + 16) = u;
        }

        if (more) {
#pragma unroll
            for (int sp = 0; sp < 4; sp++) { ba[sp] = ca[sp]; bb[sp] = cb[sp]; }
        }
    }
}

// ---------------------------------------------------------------- aggregation
// one WAVE per dst node; A is f16 row-major, 8B/lane; 8 gathers in flight,
// clamp+zero tail (extra gathers are L1 hits with w=0 -> numerically exact).

__device__ __forceinline__ float4 agg_core(const __half* __restrict__ A,
                                           const int* __restrict__ row_ptr,
                                           const int* __restrict__ col,
                                           const float* __restrict__ wgt,
                                           int node, int lane) {
    int p0 = row_ptr[node], p1 = row_ptr[node + 1];
    const __half* Al = A + lane * 4;
    float a0 = 0.f, a1 = 0.f, a2 = 0.f, a3 = 0.f;
    for (int p = p0; p < p1; p += 8) {
        int   cc[8];
        float w[8];
#pragma unroll
        for (int q = 0; q < 8; q++) {
            int idx = p + q;
            cc[q] = col[min(idx, p1 - 1)];
            w[q] = (idx < p1) ? wgt[idx] : 0.f;
        }
        uint2 u[8];
#pragma unroll
        for (int q = 0; q < 8; q++)
            u[q] = *(const uint2*)(Al + (size_t)cc[q] * DH);
#pragma unroll
        for (int q = 0; q < 8; q++) {
            float2 fa = __half22float2(*(__half2*)&u[q].x);
            float2 fb = __half22float2(*(__half2*)&u[q].y);
            a0 += w[q] * fa.x;
            a1 += w[q] * fa.y;
            a2 += w[q] * fb.x;
            a3 += w[q] * fb.y;
        }
    }
    return make_float4(a0, a1, a2, a3);
}

// variant 1: f16 output (h1, feeds gemm2)
__global__ __launch_bounds__(256) void k_agg_h(const __half* __restrict__ A,
                                               const int* __restrict__ row_ptr,
                                               const int* __restrict__ col,
                                               const float* __restrict__ wgt,
                                               const float* __restrict__ bias,
                                               __half* __restrict__ out, int n) {
    int node = (blockIdx.x << 2) + (threadIdx.x >> 6);
    int lane = threadIdx.x & 63;
    if (node >= n) return;
    node = __builtin_amdgcn_readfirstlane(node);
    float4 a = agg_core(A, row_ptr, col, wgt, node, lane);
    int f = lane * 4;
    float4 b4 = *(const float4*)&bias[f];
    __half2 h0 = __float22half2_rn(make_float2(fmaxf(a.x + b4.x, 0.f), fmaxf(a.y + b4.y, 0.f)));
    __half2 h1 = __float22half2_rn(make_float2(fmaxf(a.z + b4.z, 0.f), fmaxf(a.w + b4.w, 0.f)));
    uint2 u;
    u.x = *(unsigned int*)&h0;
    u.y = *(unsigned int*)&h1;
    *(uint2*)(out + (size_t)node * DH + f) = u;
}

// variant 2: f32 output (final h) + fused edge-predictor dot s[node]=h.We
__global__ __launch_bounds__(256) void k_agg_f(const __half* __restrict__ A,
                                               const int* __restrict__ row_ptr,
                                               const int* __restrict__ col,
                                               const float* __restrict__ wgt,
                                               const float* __restrict__ bias,
                                               const float* __restrict__ We,
                                               float* __restrict__ out,
                                               float* __restrict__ s, int n) {
    int node = (blockIdx.x << 2) + (threadIdx.x >> 6);
    int lane = threadIdx.x & 63;
    if (node >= n) return;
    node = __builtin_amdgcn_readfirstlane(node);
    float4 a = agg_core(A, row_ptr, col, wgt, node, lane);
    int f = lane * 4;
    float4 b4 = *(const float4*)&bias[f];
    float4 v = make_float4(fmaxf(a.x + b4.x, 0.f), fmaxf(a.y + b4.y, 0.f),
                           fmaxf(a.z + b4.z, 0.f), fmaxf(a.w + b4.w, 0.f));
    *(float4*)&out[(size_t)node * DH + f] = v;

    float4 wv = *(const float4*)&We[f];
    float d = v.x * wv.x + v.y * wv.y + v.z * wv.z + v.w * wv.w;
#pragma unroll
    for (int off = 32; off > 0; off >>= 1) d += __shfl_down(d, off);
    if (lane == 0) s[node] = d;
}

// ---------------------------------------------------------------- edge output

__global__ void k_y(const int* __restrict__ src, const int* __restrict__ dst,
                    const float* __restrict__ s, const float* __restrict__ be,
                    float* __restrict__ y, int e) {
    int i = blockIdx.x * blockDim.x + threadIdx.x;
    if (i < e) y[i] = 0.5f * (s[src[i]] + s[dst[i]]) + be[0];
}

// ---------------------------------------------------------------- launch

extern "C" void kernel_launch(void* const* d_in, const int* in_sizes, int n_in,
                              void* d_out, int out_size, void* d_ws, size_t ws_size,
                              hipStream_t stream) {
    const float* x  = (const float*)d_in[0];
    const int*   ei = (const int*)d_in[1];
    const float* W1 = (const float*)d_in[2];
    const float* b1 = (const float*)d_in[3];
    const float* W2 = (const float*)d_in[4];
    const float* b2 = (const float*)d_in[5];
    const float* We = (const float*)d_in[6];
    const float* be = (const float*)d_in[7];

    int n = in_sizes[0] / DH;
    int e = in_sizes[1] / 2;
    const int* src = ei;
    const int* dst = ei + e;

    float* out_h = (float*)d_out;                   // n*DH f32 (final)
    float* out_y = out_h + (size_t)n * DH;          // e
    // Xh (f16 cast of x) lives in the out_h region until agg_f overwrites it.
    _Float16* Xh = (_Float16*)d_out;

    char* w = (char*)d_ws;
    _Float16* A   = (_Float16*)w;  w += ((size_t)n * DH * 2 + 255) & ~255ull;
    _Float16* h1  = (_Float16*)w;  w += ((size_t)n * DH * 2 + 255) & ~255ull;
    _Float16* Wt1 = (_Float16*)w;  w += (size_t)DH * DH * 2;
    _Float16* Wt2 = (_Float16*)w;  w += (size_t)DH * DH * 2;
    float* deg    = (float*)w;  w += (size_t)n * 4;
    float* dinv   = (float*)w;  w += (size_t)n * 4;
    int*   row_ptr= (int*)w;    w += (size_t)(n + 1) * 4;
    int*   fill   = (int*)w;    w += (size_t)n * 4;
    int*   col    = (int*)w;    w += (size_t)(e + n + 16) * 4;   // +pad for clamp reads
    float* wgt    = (float*)w;  w += (size_t)(e + n + 16) * 4;   // +pad
    float* sbuf   = (float*)w;  w += (size_t)n * 4;
    int*   part   = (int*)w;    w += 4096;

    const int tb = 256;
    int nscan = (n + 1023) / 1024;
    k_init<<<(n + tb - 1) / tb, tb, 0, stream>>>(deg, fill, n);
    k_deg<<<(e + tb - 1) / tb, tb, 0, stream>>>(dst, deg, e);
    k_scan1<<<nscan, 1024, 0, stream>>>(deg, dinv, row_ptr, part, n);
    k_scan2<<<1, 64, 0, stream>>>(part, row_ptr, nscan, n);
    k_scan3<<<nscan, 1024, 0, stream>>>(row_ptr, part, dinv, col, wgt, fill, n);
    k_csr<<<(e + tb - 1) / tb, tb, 0, stream>>>(src, dst, dinv, row_ptr, fill, col, wgt, e);
    dim3 gt(8, 8, 2);
    k_tw<<<gt, 256, 0, stream>>>(W1, Wt1, W2, Wt2);
    k_xh<<<2048, 256, 0, stream>>>(x, Xh, (n * DH) / 8);

    int ntiles = (n + 15) / 16;
    int nblk = 512;
    int cpb = (ntiles + nblk - 1) / nblk;
    k_gemm_w<<<nblk, 512, 0, stream>>>(Xh, Wt1, A, n, ntiles, cpb);             // A = x@W1
    k_agg_h<<<(n + 3) / 4, 256, 0, stream>>>((const __half*)A, row_ptr, col, wgt, b1,
                                             (__half*)h1, n);                   // h1 (f16)
    k_gemm_w<<<nblk, 512, 0, stream>>>(h1, Wt2, A, n, ntiles, cpb);             // A = h1@W2
    k_agg_f<<<(n + 3) / 4, 256, 0, stream>>>((const __half*)A, row_ptr, col, wgt, b2,
                                             We, out_h, sbuf, n);               // final h + s
    k_y<<<(e + tb - 1) / tb, tb, 0, stream>>>(src, dst, sbuf, be, out_y, e);
}

// Round 9
// 289.186 us; speedup vs baseline: 1.5747x; 1.1067x over previous
//
#include <hip/hip_runtime.h>
#include <hip/hip_fp16.h>

#define DH 256   // feature dim (D == H == 256)

typedef _Float16 half8 __attribute__((ext_vector_type(8)));
typedef float floatx4 __attribute__((ext_vector_type(4)));

// ---------------------------------------------------------------- setup kernels

__global__ void k_init(float* __restrict__ deg, int* __restrict__ fill, int n) {
    int i = blockIdx.x * blockDim.x + threadIdx.x;
    if (i < n) { deg[i] = 1.0f; fill[i] = 0; }   // self-loop included in deg
}

__global__ void k_deg(const int* __restrict__ dst, float* __restrict__ deg, int e) {
    int i = blockIdx.x * blockDim.x + threadIdx.x;
    if (i < e) atomicAdd(&deg[dst[i]], 1.0f);
}

// ---- hierarchical exclusive scan of (int)deg -> row_ptr[0..n]; also dinv ----
__global__ __launch_bounds__(1024) void k_scan1(const float* __restrict__ deg,
                                                float* __restrict__ dinv,
                                                int* __restrict__ row_ptr,
                                                int* __restrict__ part, int n) {
    __shared__ int sd[1024];
    int tid = threadIdx.x;
    int i = blockIdx.x * 1024 + tid;
    float dv = (i < n) ? deg[i] : 1.f;
    if (i < n) dinv[i] = rsqrtf(dv);
    int v = (i < n) ? (int)dv : 0;
    sd[tid] = v;
    __syncthreads();
    for (int off = 1; off < 1024; off <<= 1) {
        int t = (tid >= off) ? sd[tid - off] : 0;
        __syncthreads();
        sd[tid] += t;
        __syncthreads();
    }
    if (i < n) row_ptr[i] = sd[tid] - v;
    if (tid == 1023) part[blockIdx.x] = sd[1023];
}

__global__ void k_scan2(int* __restrict__ part, int* __restrict__ row_ptr,
                        int nparts, int n) {
    if (threadIdx.x == 0) {
        int run = 0;
        for (int b = 0; b < nparts; b++) {
            int t = part[b];
            part[b] = run;
            run += t;
        }
        row_ptr[n] = run;
    }
}

// phase 3: add block offsets; also write self-loop CSR entry
__global__ __launch_bounds__(1024) void k_scan3(int* __restrict__ row_ptr,
                                                const int* __restrict__ part,
                                                const float* __restrict__ dinv,
                                                int* __restrict__ col,
                                                float* __restrict__ wgt,
                                                int* __restrict__ fill, int n) {
    int i = blockIdx.x * 1024 + threadIdx.x;
    if (i < n) {
        int rp = row_ptr[i] + part[blockIdx.x];
        row_ptr[i] = rp;
        col[rp] = i;
        float d = dinv[i];
        wgt[rp] = d * d;
        fill[i] = 1;
    }
}

__global__ void k_csr(const int* __restrict__ src, const int* __restrict__ dst,
                      const float* __restrict__ dinv, const int* __restrict__ row_ptr,
                      int* __restrict__ fill, int* __restrict__ col,
                      float* __restrict__ wgt, int e) {
    int i = blockIdx.x * blockDim.x + threadIdx.x;
    if (i < e) {
        int s0 = src[i], d0 = dst[i];
        int p = row_ptr[d0] + atomicAdd(&fill[d0], 1);
        col[p] = s0;
        wgt[p] = dinv[s0] * dinv[d0];
    }
}

// transpose+cast: W[k][n] f32 -> Wt[n][k] f16  (256x256); z selects weight
__global__ __launch_bounds__(256) void k_tw(const float* __restrict__ W1,
                                            _Float16* __restrict__ Wt1,
                                            const float* __restrict__ W2,
                                            _Float16* __restrict__ Wt2) {
    const float* W = blockIdx.z ? W2 : W1;
    _Float16* Wt = blockIdx.z ? Wt2 : Wt1;
    __shared__ float t[32][33];
    int bx = blockIdx.x * 32, by = blockIdx.y * 32;
    int tx = threadIdx.x & 31, ty = threadIdx.x >> 5;
#pragma unroll
    for (int r = 0; r < 32; r += 8)
        t[ty + r][tx] = W[(size_t)(by + ty + r) * DH + bx + tx];
    __syncthreads();
#pragma unroll
    for (int r = 0; r < 32; r += 8)
        Wt[(size_t)(bx + ty + r) * DH + by + tx] = (_Float16)t[tx][ty + r];
}

// cast X f32 -> f16 row-major (8 elems / thread / iter)
__global__ __launch_bounds__(256) void k_xh(const float* __restrict__ x,
                                            _Float16* __restrict__ xh, int elems8) {
    int i = blockIdx.x * blockDim.x + threadIdx.x;
    int stride = gridDim.x * blockDim.x;
    for (int j = i; j < elems8; j += stride) {
        const float* p = x + (size_t)j * 8;
        float4 a = *(const float4*)p;
        float4 b = *(const float4*)(p + 4);
        half8 h;
        h[0] = (_Float16)a.x; h[1] = (_Float16)a.y;
        h[2] = (_Float16)a.z; h[3] = (_Float16)a.w;
        h[4] = (_Float16)b.x; h[5] = (_Float16)b.y;
        h[6] = (_Float16)b.z; h[7] = (_Float16)b.w;
        *(half8*)(xh + (size_t)j * 8) = h;
    }
}

// ---------------------------------------------------------------- MFMA GEMM
// C[m][0:256] (f16) = Xh[m][0:256] @ W.  W held in registers (wfrag[2][8] per
// wave); X tile (64 rows x 512B) staged ONCE per block into LDS (dbuf 2x32KB,
// XOR-swizzled 16B granules: phys_g = g ^ (row&7) -> bank-uniform b128 ops).
// T14 split: next tile's global loads issued before compute, ds_write after.

__global__ __launch_bounds__(512, 4) void k_gemm_lds(const _Float16* __restrict__ Xh,
                                                     const _Float16* __restrict__ Wt,
                                                     _Float16* __restrict__ C,
                                                     int n, int ntiles, int cpb) {
    __shared__ _Float16 lds[2 * 64 * 256];   // 64KB
    int tid = threadIdx.x;
    int wave = tid >> 6, lane = tid & 63;
    int lm = lane & 15;        // row within 16-row fragment (D col)
    int kg = lane >> 4;        // k-group 0..3
    int c0 = wave * 32;        // wave's output-column base
    int sr = tid >> 3;         // staging row 0..63
    int sp = tid & 7;          // staging part (32 f16 = 4 granules)

    half8 wfrag[2][8];
#pragma unroll
    for (int jj = 0; jj < 2; jj++)
#pragma unroll
        for (int s = 0; s < 8; s++)
            wfrag[jj][s] = *(const half8*)(Wt + (size_t)(c0 + jj * 16 + lm) * DH + s * 32 + kg * 8);

    int tstart = blockIdx.x * cpb;
    if (tstart >= ntiles) return;
    int tend = min(tstart + cpb, ntiles);

    int sxor = sr & 7;         // staging-row swizzle
    int rxor = lm & 7;         // compute-row swizzle

    // prologue: stage tile tstart into buf 0
    {
        int m = min(tstart * 64 + sr, n - 1);
        const _Float16* g = Xh + (size_t)m * DH + sp * 32;
        half8 st[4];
#pragma unroll
        for (int j = 0; j < 4; j++) st[j] = *(const half8*)(g + j * 8);
        _Float16* d = lds + sr * 256;
#pragma unroll
        for (int j = 0; j < 4; j++)
            *(half8*)(d + (((sp * 4 + j) ^ sxor) * 8)) = st[j];
    }
    __syncthreads();

    int buf = 0;
    for (int t = tstart; t < tend; t++) {
        bool more = (t + 1) < tend;
        half8 nx[4];
        if (more) {
            int m = min((t + 1) * 64 + sr, n - 1);
            const _Float16* g = Xh + (size_t)m * DH + sp * 32;
#pragma unroll
            for (int j = 0; j < 4; j++) nx[j] = *(const half8*)(g + j * 8);
        }

        const _Float16* lb = lds + buf * (64 * 256);
#pragma unroll
        for (int rf = 0; rf < 4; rf++) {
            floatx4 a0 = {0.f, 0.f, 0.f, 0.f};
            floatx4 a1 = {0.f, 0.f, 0.f, 0.f};
            const _Float16* lrow = lb + (rf * 16 + lm) * 256;
#pragma unroll
            for (int s = 0; s < 8; s++) {
                half8 b = *(const half8*)(lrow + (((s * 4 + kg) ^ rxor) * 8));
                a0 = __builtin_amdgcn_mfma_f32_16x16x32_f16(wfrag[0][s], b, a0, 0, 0, 0);
                a1 = __builtin_amdgcn_mfma_f32_16x16x32_f16(wfrag[1][s], b, a1, 0, 0, 0);
            }
            int m = t * 64 + rf * 16 + lm;
            if (m < n) {
                _Float16* crow = C + (size_t)m * DH + c0 + kg * 4;
                __half2 h0 = __float22half2_rn(make_float2(a0[0], a0[1]));
                __half2 h1 = __float22half2_rn(make_float2(a0[2], a0[3]));
                uint2 u;
                u.x = *(unsigned int*)&h0; u.y = *(unsigned int*)&h1;
                *(uint2*)crow = u;
                h0 = __float22half2_rn(make_float2(a1[0], a1[1]));
                h1 = __float22half2_rn(make_float2(a1[2], a1[3]));
                u.x = *(unsigned int*)&h0; u.y = *(unsigned int*)&h1;
                *(uint2*)(crow + 16) = u;
            }
        }

        if (more) {
            __syncthreads();                       // all waves done reading buf^1
            _Float16* d = lds + (buf ^ 1) * (64 * 256) + sr * 256;
#pragma unroll
            for (int j = 0; j < 4; j++)
                *(half8*)(d + (((sp * 4 + j) ^ sxor) * 8)) = nx[j];
            __syncthreads();                       // writes visible
            buf ^= 1;
        }
    }
}

// ---------------------------------------------------------------- aggregation
// one WAVE per dst node; A is f16 row-major, 8B/lane; 8 gathers in flight,
// clamp+zero tail (extra gathers are L1 hits with w=0 -> numerically exact).

__device__ __forceinline__ float4 agg_core(const __half* __restrict__ A,
                                           const int* __restrict__ row_ptr,
                                           const int* __restrict__ col,
                                           const float* __restrict__ wgt,
                                           int node, int lane) {
    int p0 = row_ptr[node], p1 = row_ptr[node + 1];
    const __half* Al = A + lane * 4;
    float a0 = 0.f, a1 = 0.f, a2 = 0.f, a3 = 0.f;
    for (int p = p0; p < p1; p += 8) {
        int   cc[8];
        float w[8];
#pragma unroll
        for (int q = 0; q < 8; q++) {
            int idx = p + q;
            cc[q] = col[min(idx, p1 - 1)];
            w[q] = (idx < p1) ? wgt[idx] : 0.f;
        }
        uint2 u[8];
#pragma unroll
        for (int q = 0; q < 8; q++)
            u[q] = *(const uint2*)(Al + (size_t)cc[q] * DH);
#pragma unroll
        for (int q = 0; q < 8; q++) {
            float2 fa = __half22float2(*(__half2*)&u[q].x);
            float2 fb = __half22float2(*(__half2*)&u[q].y);
            a0 += w[q] * fa.x;
            a1 += w[q] * fa.y;
            a2 += w[q] * fb.x;
            a3 += w[q] * fb.y;
        }
    }
    return make_float4(a0, a1, a2, a3);
}

// variant 1: f16 output (h1, feeds gemm2)
__global__ __launch_bounds__(256) void k_agg_h(const __half* __restrict__ A,
                                               const int* __restrict__ row_ptr,
                                               const int* __restrict__ col,
                                               const float* __restrict__ wgt,
                                               const float* __restrict__ bias,
                                               __half* __restrict__ out, int n) {
    int node = (blockIdx.x << 2) + (threadIdx.x >> 6);
    int lane = threadIdx.x & 63;
    if (node >= n) return;
    node = __builtin_amdgcn_readfirstlane(node);
    float4 a = agg_core(A, row_ptr, col, wgt, node, lane);
    int f = lane * 4;
    float4 b4 = *(const float4*)&bias[f];
    __half2 h0 = __float22half2_rn(make_float2(fmaxf(a.x + b4.x, 0.f), fmaxf(a.y + b4.y, 0.f)));
    __half2 h1 = __float22half2_rn(make_float2(fmaxf(a.z + b4.z, 0.f), fmaxf(a.w + b4.w, 0.f)));
    uint2 u;
    u.x = *(unsigned int*)&h0;
    u.y = *(unsigned int*)&h1;
    *(uint2*)(out + (size_t)node * DH + f) = u;
}

// variant 2: f32 output (final h) + fused edge-predictor dot s[node]=h.We
__global__ __launch_bounds__(256) void k_agg_f(const __half* __restrict__ A,
                                               const int* __restrict__ row_ptr,
                                               const int* __restrict__ col,
                                               const float* __restrict__ wgt,
                                               const float* __restrict__ bias,
                                               const float* __restrict__ We,
                                               float* __restrict__ out,
                                               float* __restrict__ s, int n) {
    int node = (blockIdx.x << 2) + (threadIdx.x >> 6);
    int lane = threadIdx.x & 63;
    if (node >= n) return;
    node = __builtin_amdgcn_readfirstlane(node);
    float4 a = agg_core(A, row_ptr, col, wgt, node, lane);
    int f = lane * 4;
    float4 b4 = *(const float4*)&bias[f];
    float4 v = make_float4(fmaxf(a.x + b4.x, 0.f), fmaxf(a.y + b4.y, 0.f),
                           fmaxf(a.z + b4.z, 0.f), fmaxf(a.w + b4.w, 0.f));
    *(float4*)&out[(size_t)node * DH + f] = v;

    float4 wv = *(const float4*)&We[f];
    float d = v.x * wv.x + v.y * wv.y + v.z * wv.z + v.w * wv.w;
#pragma unroll
    for (int off = 32; off > 0; off >>= 1) d += __shfl_down(d, off);
    if (lane == 0) s[node] = d;
}

// ---------------------------------------------------------------- edge output

__global__ void k_y(const int* __restrict__ src, const int* __restrict__ dst,
                    const float* __restrict__ s, const float* __restrict__ be,
                    float* __restrict__ y, int e) {
    int i = blockIdx.x * blockDim.x + threadIdx.x;
    if (i < e) y[i] = 0.5f * (s[src[i]] + s[dst[i]]) + be[0];
}

// ---------------------------------------------------------------- launch

extern "C" void kernel_launch(void* const* d_in, const int* in_sizes, int n_in,
                              void* d_out, int out_size, void* d_ws, size_t ws_size,
                              hipStream_t stream) {
    const float* x  = (const float*)d_in[0];
    const int*   ei = (const int*)d_in[1];
    const float* W1 = (const float*)d_in[2];
    const float* b1 = (const float*)d_in[3];
    const float* W2 = (const float*)d_in[4];
    const float* b2 = (const float*)d_in[5];
    const float* We = (const float*)d_in[6];
    const float* be = (const float*)d_in[7];

    int n = in_sizes[0] / DH;
    int e = in_sizes[1] / 2;
    const int* src = ei;
    const int* dst = ei + e;

    float* out_h = (float*)d_out;                   // n*DH f32 (final)
    float* out_y = out_h + (size_t)n * DH;          // e
    // Xh (f16 cast of x) lives in the out_h region until agg_f overwrites it.
    _Float16* Xh = (_Float16*)d_out;

    char* w = (char*)d_ws;
    _Float16* A   = (_Float16*)w;  w += ((size_t)n * DH * 2 + 255) & ~255ull;
    _Float16* h1  = (_Float16*)w;  w += ((size_t)n * DH * 2 + 255) & ~255ull;
    _Float16* Wt1 = (_Float16*)w;  w += (size_t)DH * DH * 2;
    _Float16* Wt2 = (_Float16*)w;  w += (size_t)DH * DH * 2;
    float* deg    = (float*)w;  w += (size_t)n * 4;
    float* dinv   = (float*)w;  w += (size_t)n * 4;
    int*   row_ptr= (int*)w;    w += (size_t)(n + 1) * 4;
    int*   fill   = (int*)w;    w += (size_t)n * 4;
    int*   col    = (int*)w;    w += (size_t)(e + n + 16) * 4;   // +pad for clamp reads
    float* wgt    = (float*)w;  w += (size_t)(e + n + 16) * 4;   // +pad
    float* sbuf   = (float*)w;  w += (size_t)n * 4;
    int*   part   = (int*)w;    w += 4096;

    const int tb = 256;
    int nscan = (n + 1023) / 1024;
    k_init<<<(n + tb - 1) / tb, tb, 0, stream>>>(deg, fill, n);
    k_deg<<<(e + tb - 1) / tb, tb, 0, stream>>>(dst, deg, e);
    k_scan1<<<nscan, 1024, 0, stream>>>(deg, dinv, row_ptr, part, n);
    k_scan2<<<1, 64, 0, stream>>>(part, row_ptr, nscan, n);
    k_scan3<<<nscan, 1024, 0, stream>>>(row_ptr, part, dinv, col, wgt, fill, n);
    k_csr<<<(e + tb - 1) / tb, tb, 0, stream>>>(src, dst, dinv, row_ptr, fill, col, wgt, e);
    dim3 gt(8, 8, 2);
    k_tw<<<gt, 256, 0, stream>>>(W1, Wt1, W2, Wt2);
    k_xh<<<2048, 256, 0, stream>>>(x, Xh, (n * DH) / 8);

    int ntiles = (n + 63) / 64;          // 64-row tiles
    int cpb = 2;
    int nblk = (ntiles + cpb - 1) / cpb;
    k_gemm_lds<<<nblk, 512, 0, stream>>>(Xh, Wt1, A, n, ntiles, cpb);           // A = x@W1
    k_agg_h<<<(n + 3) / 4, 256, 0, stream>>>((const __half*)A, row_ptr, col, wgt, b1,
                                             (__half*)h1, n);                   // h1 (f16)
    k_gemm_lds<<<nblk, 512, 0, stream>>>(h1, Wt2, A, n, ntiles, cpb);           // A = h1@W2
    k_agg_f<<<(n + 3) / 4, 256, 0, stream>>>((const __half*)A, row_ptr, col, wgt, b2,
                                             We, out_h, sbuf, n);               // final h + s
    k_y<<<(e + tb - 1) / tb, tb, 0, stream>>>(src, dst, sbuf, be, out_y, e);
}

// Round 10
// 285.853 us; speedup vs baseline: 1.5931x; 1.0117x over previous
//
#include <hip/hip_runtime.h>
#include <hip/hip_fp16.h>

#define DH 256   // feature dim (D == H == 256)

typedef _Float16 half8 __attribute__((ext_vector_type(8)));
typedef float floatx4 __attribute__((ext_vector_type(4)));

// ---------------------------------------------------------------- setup kernels

__global__ void k_init(float* __restrict__ deg, int* __restrict__ fill, int n) {
    int i = blockIdx.x * blockDim.x + threadIdx.x;
    if (i < n) { deg[i] = 1.0f; fill[i] = 0; }   // self-loop included in deg
}

__global__ void k_deg(const int* __restrict__ dst, float* __restrict__ deg, int e) {
    int i = blockIdx.x * blockDim.x + threadIdx.x;
    if (i < e) atomicAdd(&deg[dst[i]], 1.0f);
}

// ---- hierarchical exclusive scan of (int)deg -> row_ptr[0..n]; also dinv ----
__global__ __launch_bounds__(1024) void k_scan1(const float* __restrict__ deg,
                                                float* __restrict__ dinv,
                                                int* __restrict__ row_ptr,
                                                int* __restrict__ part, int n) {
    __shared__ int sd[1024];
    int tid = threadIdx.x;
    int i = blockIdx.x * 1024 + tid;
    float dv = (i < n) ? deg[i] : 1.f;
    if (i < n) dinv[i] = rsqrtf(dv);
    int v = (i < n) ? (int)dv : 0;
    sd[tid] = v;
    __syncthreads();
    for (int off = 1; off < 1024; off <<= 1) {
        int t = (tid >= off) ? sd[tid - off] : 0;
        __syncthreads();
        sd[tid] += t;
        __syncthreads();
    }
    if (i < n) row_ptr[i] = sd[tid] - v;
    if (tid == 1023) part[blockIdx.x] = sd[1023];
}

// single-wave shuffle scan of block totals (nparts can exceed 64 via carry loop)
__global__ void k_scan2(int* __restrict__ part, int* __restrict__ row_ptr,
                        int nparts, int n) {
    int lane = threadIdx.x & 63;
    int carry = 0;
    for (int base = 0; base < nparts; base += 64) {
        int i = base + lane;
        int v = (i < nparts) ? part[i] : 0;
        int orig = v;
        for (int off = 1; off < 64; off <<= 1) {
            int t = __shfl_up(v, off);
            if (lane >= off) v += t;
        }
        if (i < nparts) part[i] = carry + v - orig;   // exclusive
        int tot = __shfl(v, 63);
        carry += tot;
    }
    if (lane == 0) row_ptr[n] = carry;
}

// phase 3: add block offsets; also write self-loop CSR entry
__global__ __launch_bounds__(1024) void k_scan3(int* __restrict__ row_ptr,
                                                const int* __restrict__ part,
                                                const float* __restrict__ dinv,
                                                int* __restrict__ col,
                                                float* __restrict__ wgt,
                                                int* __restrict__ fill, int n) {
    int i = blockIdx.x * 1024 + threadIdx.x;
    if (i < n) {
        int rp = row_ptr[i] + part[blockIdx.x];
        row_ptr[i] = rp;
        col[rp] = i;
        float d = dinv[i];
        wgt[rp] = d * d;
        fill[i] = 1;
    }
}

__global__ void k_csr(const int* __restrict__ src, const int* __restrict__ dst,
                      const float* __restrict__ dinv, const int* __restrict__ row_ptr,
                      int* __restrict__ fill, int* __restrict__ col,
                      float* __restrict__ wgt, int e) {
    int i = blockIdx.x * blockDim.x + threadIdx.x;
    if (i < e) {
        int s0 = src[i], d0 = dst[i];
        int p = row_ptr[d0] + atomicAdd(&fill[d0], 1);
        col[p] = s0;
        wgt[p] = dinv[s0] * dinv[d0];
    }
}

// transpose+cast: W[k][n] f32 -> Wt[n][k] f16  (256x256); z selects weight
__global__ __launch_bounds__(256) void k_tw(const float* __restrict__ W1,
                                            _Float16* __restrict__ Wt1,
                                            const float* __restrict__ W2,
                                            _Float16* __restrict__ Wt2) {
    const float* W = blockIdx.z ? W2 : W1;
    _Float16* Wt = blockIdx.z ? Wt2 : Wt1;
    __shared__ float t[32][33];
    int bx = blockIdx.x * 32, by = blockIdx.y * 32;
    int tx = threadIdx.x & 31, ty = threadIdx.x >> 5;
#pragma unroll
    for (int r = 0; r < 32; r += 8)
        t[ty + r][tx] = W[(size_t)(by + ty + r) * DH + bx + tx];
    __syncthreads();
#pragma unroll
    for (int r = 0; r < 32; r += 8)
        Wt[(size_t)(bx + ty + r) * DH + by + tx] = (_Float16)t[tx][ty + r];
}

// ---------------------------------------------------------------- MFMA GEMM
// C[m][0:256] (f16) = X[m][0:256] @ W.  W held in registers (wfrag[2][8] per
// wave); X tile (64 rows) staged ONCE per block into LDS (dbuf 2x32KB,
// XOR-swizzled 16B granules). AF32 variant reads f32 input and converts
// during staging (fuses the x->f16 cast into gemm1).

template <bool AF32>
__global__ __launch_bounds__(512, 4) void k_gemm_lds(const void* __restrict__ Av,
                                                     const _Float16* __restrict__ Wt,
                                                     _Float16* __restrict__ C,
                                                     int n, int ntiles, int cpb) {
    __shared__ _Float16 lds[2 * 64 * 256];   // 64KB
    int tid = threadIdx.x;
    int wave = tid >> 6, lane = tid & 63;
    int lm = lane & 15;        // row within 16-row fragment (D col)
    int kg = lane >> 4;        // k-group 0..3
    int c0 = wave * 32;        // wave's output-column base
    int sr = tid >> 3;         // staging row 0..63
    int sp = tid & 7;          // staging part (32 f16 = 4 granules)

    const float*    Af = (const float*)Av;
    const _Float16* Ah = (const _Float16*)Av;

    half8 wfrag[2][8];
#pragma unroll
    for (int jj = 0; jj < 2; jj++)
#pragma unroll
        for (int s = 0; s < 8; s++)
            wfrag[jj][s] = *(const half8*)(Wt + (size_t)(c0 + jj * 16 + lm) * DH + s * 32 + kg * 8);

    int tstart = blockIdx.x * cpb;
    if (tstart >= ntiles) return;
    int tend = min(tstart + cpb, ntiles);

    int sxor = sr & 7;         // staging-row swizzle
    int rxor = lm & 7;         // compute-row swizzle

    // prologue: stage tile tstart into buf 0
    {
        int m = min(tstart * 64 + sr, n - 1);
        half8 st[4];
        if (AF32) {
            const float* g = Af + (size_t)m * DH + sp * 32;
#pragma unroll
            for (int j = 0; j < 4; j++) {
                float4 a = *(const float4*)(g + j * 8);
                float4 b = *(const float4*)(g + j * 8 + 4);
                st[j][0] = (_Float16)a.x; st[j][1] = (_Float16)a.y;
                st[j][2] = (_Float16)a.z; st[j][3] = (_Float16)a.w;
                st[j][4] = (_Float16)b.x; st[j][5] = (_Float16)b.y;
                st[j][6] = (_Float16)b.z; st[j][7] = (_Float16)b.w;
            }
        } else {
            const _Float16* g = Ah + (size_t)m * DH + sp * 32;
#pragma unroll
            for (int j = 0; j < 4; j++) st[j] = *(const half8*)(g + j * 8);
        }
        _Float16* d = lds + sr * 256;
#pragma unroll
        for (int j = 0; j < 4; j++)
            *(half8*)(d + (((sp * 4 + j) ^ sxor) * 8)) = st[j];
    }
    __syncthreads();

    int buf = 0;
    for (int t = tstart; t < tend; t++) {
        bool more = (t + 1) < tend;
        float4 nf[8];
        half8  nh[4];
        if (more) {
            int m = min((t + 1) * 64 + sr, n - 1);
            if (AF32) {
                const float* g = Af + (size_t)m * DH + sp * 32;
#pragma unroll
                for (int j = 0; j < 8; j++) nf[j] = *(const float4*)(g + j * 4);
            } else {
                const _Float16* g = Ah + (size_t)m * DH + sp * 32;
#pragma unroll
                for (int j = 0; j < 4; j++) nh[j] = *(const half8*)(g + j * 8);
            }
        }

        const _Float16* lb = lds + buf * (64 * 256);
#pragma unroll
        for (int rf = 0; rf < 4; rf++) {
            floatx4 a0 = {0.f, 0.f, 0.f, 0.f};
            floatx4 a1 = {0.f, 0.f, 0.f, 0.f};
            const _Float16* lrow = lb + (rf * 16 + lm) * 256;
#pragma unroll
            for (int s = 0; s < 8; s++) {
                half8 b = *(const half8*)(lrow + (((s * 4 + kg) ^ rxor) * 8));
                a0 = __builtin_amdgcn_mfma_f32_16x16x32_f16(wfrag[0][s], b, a0, 0, 0, 0);
                a1 = __builtin_amdgcn_mfma_f32_16x16x32_f16(wfrag[1][s], b, a1, 0, 0, 0);
            }
            int m = t * 64 + rf * 16 + lm;
            if (m < n) {
                _Float16* crow = C + (size_t)m * DH + c0 + kg * 4;
                __half2 h0 = __float22half2_rn(make_float2(a0[0], a0[1]));
                __half2 h1 = __float22half2_rn(make_float2(a0[2], a0[3]));
                uint2 u;
                u.x = *(unsigned int*)&h0; u.y = *(unsigned int*)&h1;
                *(uint2*)crow = u;
                h0 = __float22half2_rn(make_float2(a1[0], a1[1]));
                h1 = __float22half2_rn(make_float2(a1[2], a1[3]));
                u.x = *(unsigned int*)&h0; u.y = *(unsigned int*)&h1;
                *(uint2*)(crow + 16) = u;
            }
        }

        if (more) {
            __syncthreads();                       // all waves done reading buf^1
            _Float16* d = lds + (buf ^ 1) * (64 * 256) + sr * 256;
            if (AF32) {
#pragma unroll
                for (int j = 0; j < 4; j++) {
                    float4 a = nf[2 * j], b = nf[2 * j + 1];
                    half8 st;
                    st[0] = (_Float16)a.x; st[1] = (_Float16)a.y;
                    st[2] = (_Float16)a.z; st[3] = (_Float16)a.w;
                    st[4] = (_Float16)b.x; st[5] = (_Float16)b.y;
                    st[6] = (_Float16)b.z; st[7] = (_Float16)b.w;
                    *(half8*)(d + (((sp * 4 + j) ^ sxor) * 8)) = st;
                }
            } else {
#pragma unroll
                for (int j = 0; j < 4; j++)
                    *(half8*)(d + (((sp * 4 + j) ^ sxor) * 8)) = nh[j];
            }
            __syncthreads();                       // writes visible
            buf ^= 1;
        }
    }
}

// ---------------------------------------------------------------- aggregation
// one WAVE per dst node. Lane q holds col/wgt of edge p0+q (ONE vector load
// per 64 edges); each edge's col is broadcast via shfl (readlane) -> gathers
// use SGPR-base addressing and issue back-to-back, no s_load serialization.
// Clamped lanes get w=0 (exact); clamped gathers hit L1.

__device__ __forceinline__ float4 agg_core(const __half* __restrict__ A,
                                           const int* __restrict__ row_ptr,
                                           const int* __restrict__ col,
                                           const float* __restrict__ wgt,
                                           int node, int lane) {
    int p0 = row_ptr[node], p1 = row_ptr[node + 1];
    const __half* Al = A + lane * 4;
    float a0 = 0.f, a1 = 0.f, a2 = 0.f, a3 = 0.f;
    for (int base = p0; base < p1; base += 64) {
        int idx = base + lane;
        int   cl = col[min(idx, p1 - 1)];         // vector load: 64 cols
        float wl = (idx < p1) ? wgt[idx] : 0.f;   // vector load: 64 weights
        int cnt = min(p1 - base, 64);
        for (int q0 = 0; q0 < cnt; q0 += 8) {
            uint2 u[8];
            float w[8];
#pragma unroll
            for (int q = 0; q < 8; q++) {
                int c = __shfl(cl, q0 + q);       // broadcast (readlane)
                w[q] = __shfl(wl, q0 + q);
                u[q] = *(const uint2*)(Al + (size_t)c * DH);
            }
#pragma unroll
            for (int q = 0; q < 8; q++) {
                float2 fa = __half22float2(*(__half2*)&u[q].x);
                float2 fb = __half22float2(*(__half2*)&u[q].y);
                a0 += w[q] * fa.x;
                a1 += w[q] * fa.y;
                a2 += w[q] * fb.x;
                a3 += w[q] * fb.y;
            }
        }
    }
    return make_float4(a0, a1, a2, a3);
}

// variant 1: f16 output (h1, feeds gemm2)
__global__ __launch_bounds__(256) void k_agg_h(const __half* __restrict__ A,
                                               const int* __restrict__ row_ptr,
                                               const int* __restrict__ col,
                                               const float* __restrict__ wgt,
                                               const float* __restrict__ bias,
                                               __half* __restrict__ out, int n) {
    int node = (blockIdx.x << 2) + (threadIdx.x >> 6);
    int lane = threadIdx.x & 63;
    if (node >= n) return;
    node = __builtin_amdgcn_readfirstlane(node);
    float4 a = agg_core(A, row_ptr, col, wgt, node, lane);
    int f = lane * 4;
    float4 b4 = *(const float4*)&bias[f];
    __half2 h0 = __float22half2_rn(make_float2(fmaxf(a.x + b4.x, 0.f), fmaxf(a.y + b4.y, 0.f)));
    __half2 h1 = __float22half2_rn(make_float2(fmaxf(a.z + b4.z, 0.f), fmaxf(a.w + b4.w, 0.f)));
    uint2 u;
    u.x = *(unsigned int*)&h0;
    u.y = *(unsigned int*)&h1;
    *(uint2*)(out + (size_t)node * DH + f) = u;
}

// variant 2: f32 output (final h) + fused edge-predictor dot s[node]=h.We
__global__ __launch_bounds__(256) void k_agg_f(const __half* __restrict__ A,
                                               const int* __restrict__ row_ptr,
                                               const int* __restrict__ col,
                                               const float* __restrict__ wgt,
                                               const float* __restrict__ bias,
                                               const float* __restrict__ We,
                                               float* __restrict__ out,
                                               float* __restrict__ s, int n) {
    int node = (blockIdx.x << 2) + (threadIdx.x >> 6);
    int lane = threadIdx.x & 63;
    if (node >= n) return;
    node = __builtin_amdgcn_readfirstlane(node);
    float4 a = agg_core(A, row_ptr, col, wgt, node, lane);
    int f = lane * 4;
    float4 b4 = *(const float4*)&bias[f];
    float4 v = make_float4(fmaxf(a.x + b4.x, 0.f), fmaxf(a.y + b4.y, 0.f),
                           fmaxf(a.z + b4.z, 0.f), fmaxf(a.w + b4.w, 0.f));
    *(float4*)&out[(size_t)node * DH + f] = v;

    float4 wv = *(const float4*)&We[f];
    float d = v.x * wv.x + v.y * wv.y + v.z * wv.z + v.w * wv.w;
#pragma unroll
    for (int off = 32; off > 0; off >>= 1) d += __shfl_down(d, off);
    if (lane == 0) s[node] = d;
}

// ---------------------------------------------------------------- edge output

__global__ void k_y(const int* __restrict__ src, const int* __restrict__ dst,
                    const float* __restrict__ s, const float* __restrict__ be,
                    float* __restrict__ y, int e) {
    int i = blockIdx.x * blockDim.x + threadIdx.x;
    if (i < e) y[i] = 0.5f * (s[src[i]] + s[dst[i]]) + be[0];
}

// ---------------------------------------------------------------- launch

extern "C" void kernel_launch(void* const* d_in, const int* in_sizes, int n_in,
                              void* d_out, int out_size, void* d_ws, size_t ws_size,
                              hipStream_t stream) {
    const float* x  = (const float*)d_in[0];
    const int*   ei = (const int*)d_in[1];
    const float* W1 = (const float*)d_in[2];
    const float* b1 = (const float*)d_in[3];
    const float* W2 = (const float*)d_in[4];
    const float* b2 = (const float*)d_in[5];
    const float* We = (const float*)d_in[6];
    const float* be = (const float*)d_in[7];

    int n = in_sizes[0] / DH;
    int e = in_sizes[1] / 2;
    const int* src = ei;
    const int* dst = ei + e;

    float* out_h = (float*)d_out;                   // n*DH f32 (final)
    float* out_y = out_h + (size_t)n * DH;          // e

    char* w = (char*)d_ws;
    _Float16* A   = (_Float16*)w;  w += ((size_t)n * DH * 2 + 255) & ~255ull;
    _Float16* h1  = (_Float16*)w;  w += ((size_t)n * DH * 2 + 255) & ~255ull;
    _Float16* Wt1 = (_Float16*)w;  w += (size_t)DH * DH * 2;
    _Float16* Wt2 = (_Float16*)w;  w += (size_t)DH * DH * 2;
    float* deg    = (float*)w;  w += (size_t)n * 4;
    float* dinv   = (float*)w;  w += (size_t)n * 4;
    int*   row_ptr= (int*)w;    w += (size_t)(n + 1) * 4;
    int*   fill   = (int*)w;    w += (size_t)n * 4;
    int*   col    = (int*)w;    w += (size_t)(e + n + 64) * 4;   // +pad for clamp reads
    float* wgt    = (float*)w;  w += (size_t)(e + n + 64) * 4;   // +pad
    float* sbuf   = (float*)w;  w += (size_t)n * 4;
    int*   part   = (int*)w;    w += 4096;

    const int tb = 256;
    int nscan = (n + 1023) / 1024;
    k_init<<<(n + tb - 1) / tb, tb, 0, stream>>>(deg, fill, n);
    k_deg<<<(e + tb - 1) / tb, tb, 0, stream>>>(dst, deg, e);
    k_scan1<<<nscan, 1024, 0, stream>>>(deg, dinv, row_ptr, part, n);
    k_scan2<<<1, 64, 0, stream>>>(part, row_ptr, nscan, n);
    k_scan3<<<nscan, 1024, 0, stream>>>(row_ptr, part, dinv, col, wgt, fill, n);
    k_csr<<<(e + tb - 1) / tb, tb, 0, stream>>>(src, dst, dinv, row_ptr, fill, col, wgt, e);
    dim3 gt(8, 8, 2);
    k_tw<<<gt, 256, 0, stream>>>(W1, Wt1, W2, Wt2);

    int ntiles = (n + 63) / 64;          // 64-row tiles
    int cpb = 2;
    int nblk = (ntiles + cpb - 1) / cpb;
    k_gemm_lds<true><<<nblk, 512, 0, stream>>>(x, Wt1, A, n, ntiles, cpb);      // A = x@W1 (cast fused)
    k_agg_h<<<(n + 3) / 4, 256, 0, stream>>>((const __half*)A, row_ptr, col, wgt, b1,
                                             (__half*)h1, n);                   // h1 (f16)
    k_gemm_lds<false><<<nblk, 512, 0, stream>>>(h1, Wt2, A, n, ntiles, cpb);    // A = h1@W2
    k_agg_f<<<(n + 3) / 4, 256, 0, stream>>>((const __half*)A, row_ptr, col, wgt, b2,
                                             We, out_h, sbuf, n);               // final h + s
    k_y<<<(e + tb - 1) / tb, tb, 0, stream>>>(src, dst, sbuf, be, out_y, e);
}